// Round 1
// baseline (59.155 us; speedup 1.0000x reference)
//
#include <hip/hip_runtime.h>
#include <cstddef>
#include <cstdint>

#define NROWS 200000
#define CIN   32
#define COUT  64
#define KV    27

typedef __attribute__((ext_vector_type(8))) short  short8;
typedef __attribute__((ext_vector_type(4))) float  f32x4;

// RNE float -> bf16 (inputs are finite; NaN path not needed)
__device__ __forceinline__ unsigned short f2bf(float x) {
  unsigned u = __builtin_bit_cast(unsigned, x);
  u += 0x7FFFu + ((u >> 16) & 1u);
  return (unsigned short)(u >> 16);
}

// Pack weight [27][32][64] f32 -> bf16 B-fragments, exact mfma_16x16x32 B layout:
// wsB[(k*4+t)*64 + lane][f] = W[k][(lane>>4)*8+f][t*16+(lane&15)]
__global__ void prep_weight_kernel(const float* __restrict__ w,
                                   short8* __restrict__ wsB) {
  int tid = blockIdx.x * blockDim.x + threadIdx.x;   // 27*4*64 = 6912 threads
  if (tid >= KV * 4 * 64) return;
  int lane = tid & 63;
  int t    = (tid >> 6) & 3;
  int k    = tid >> 8;
  int col  = t * 16 + (lane & 15);
  int kin0 = (lane >> 4) * 8;
  short8 v;
#pragma unroll
  for (int f = 0; f < 8; ++f)
    v[f] = (short)f2bf(w[((size_t)k * CIN + kin0 + f) * COUT + col]);
  wsB[tid] = v;
}

// feats f32 [N][32] -> bf16 [N+1][32]; row N (pad) = zeros.
__global__ void prep_feats_kernel(const float* __restrict__ feats,
                                  short8* __restrict__ fb) {
  int i = blockIdx.x * blockDim.x + threadIdx.x;     // one short8 (8 elems) each
  const int total8 = (NROWS + 1) * CIN / 8;          // 800004
  if (i >= total8) return;
  short8 v = {0, 0, 0, 0, 0, 0, 0, 0};
  if (i < NROWS * CIN / 8) {
    const f32x4* p = (const f32x4*)feats + (size_t)i * 2;
    f32x4 a = p[0], b = p[1];
#pragma unroll
    for (int f = 0; f < 4; ++f) {
      v[f]     = (short)f2bf(a[f]);
      v[4 + f] = (short)f2bf(b[f]);
    }
  }
  fb[i] = v;
}

// Main: 1 wave = 4 M-tiles (64 rows) x full COUT=64 (4 N-tiles).
// A-frag gather: lane loads 16B from featsbf[idx(row)] at k-offset (lane>>4)*8
//   -> exactly the mfma A layout (row = lane&15, k = (lane>>4)*8 + f).
// MODE 0: pre-converted bf16 feats (pad row = zeros, no branch).
// MODE 1: gather fp32 feats, convert in-register, branch on pad.
template <int MODE>
__global__ __launch_bounds__(256)
void spconv_mfma_kernel(const float* __restrict__ feats,
                        const unsigned short* __restrict__ featsbf,
                        const short8* __restrict__ wsB,
                        const float* __restrict__ bias,
                        const int* __restrict__ in_idx,
                        float* __restrict__ out) {
  const int lane = threadIdx.x & 63;
  const int wid  = (int)((blockIdx.x * blockDim.x + threadIdx.x) >> 6);
  if (wid >= NROWS / 64) return;                     // 3125 waves
  const int row0 = wid * 64;
  const int c16  = lane & 15;
  const int kg   = lane >> 4;

  f32x4 acc[4][4];                                   // [m-tile][n-tile]
#pragma unroll
  for (int t = 0; t < 4; ++t) {
    float bv = bias[t * 16 + c16];                   // D: col = lane&15
    f32x4 bvv = {bv, bv, bv, bv};
#pragma unroll
    for (int m = 0; m < 4; ++m) acc[m][t] = bvv;
  }

  for (int k = 0; k < KV; ++k) {
    short8 bfr[4];
#pragma unroll
    for (int t = 0; t < 4; ++t) bfr[t] = wsB[(k * 4 + t) * 64 + lane];
#pragma unroll
    for (int m = 0; m < 4; ++m) {
      const int idx = in_idx[(size_t)k * NROWS + row0 + m * 16 + c16];
      short8 afr;
      if (MODE == 0) {
        afr = *(const short8*)(featsbf + (size_t)idx * CIN + kg * 8);
      } else {
        short8 z = {0, 0, 0, 0, 0, 0, 0, 0};
        afr = z;
        if (idx < NROWS) {
          const f32x4* p = (const f32x4*)(feats + (size_t)idx * CIN + kg * 8);
          f32x4 a = p[0], b = p[1];
#pragma unroll
          for (int f = 0; f < 4; ++f) {
            afr[f]     = (short)f2bf(a[f]);
            afr[4 + f] = (short)f2bf(b[f]);
          }
        }
      }
#pragma unroll
      for (int t = 0; t < 4; ++t)
        acc[m][t] = __builtin_amdgcn_mfma_f32_16x16x32_bf16(afr, bfr[t], acc[m][t], 0, 0, 0);
    }
  }

  // D layout: col = lane&15, row = (lane>>4)*4 + r
#pragma unroll
  for (int m = 0; m < 4; ++m)
#pragma unroll
    for (int t = 0; t < 4; ++t)
#pragma unroll
      for (int r = 0; r < 4; ++r)
        out[(size_t)(row0 + m * 16 + kg * 4 + r) * COUT + t * 16 + c16] = acc[m][t][r];
}

// Correct-but-slow fallback if ws is tiny (shouldn't happen).
__global__ void spconv_naive_kernel(const float* __restrict__ feats,
                                    const float* __restrict__ w,
                                    const float* __restrict__ bias,
                                    const int* __restrict__ in_idx,
                                    float* __restrict__ out) {
  int gid = blockIdx.x * blockDim.x + threadIdx.x;
  if (gid >= NROWS * COUT) return;
  int row = gid / COUT, co = gid % COUT;
  float acc = bias[co];
  for (int k = 0; k < KV; ++k) {
    int idx = in_idx[(size_t)k * NROWS + row];
    if (idx < NROWS) {
      const float* fr = feats + (size_t)idx * CIN;
      const float* wk = w + (size_t)k * CIN * COUT + co;
#pragma unroll
      for (int c = 0; c < CIN; ++c) acc += fr[c] * wk[(size_t)c * COUT];
    }
  }
  out[gid] = acc;
}

extern "C" void kernel_launch(void* const* d_in, const int* in_sizes, int n_in,
                              void* d_out, int out_size, void* d_ws, size_t ws_size,
                              hipStream_t stream) {
  const float* feats  = (const float*)d_in[0];
  const float* weight = (const float*)d_in[1];
  const float* bias   = (const float*)d_in[2];
  const int*   in_idx = (const int*)d_in[3];
  float*       out    = (float*)d_out;

  const size_t wsB_bytes = (size_t)KV * 4 * 64 * 16;        // 110592
  const size_t fb_bytes  = (size_t)(NROWS + 1) * CIN * 2;   // 12800064
  short8*         wsB     = (short8*)d_ws;
  unsigned short* featsbf = (unsigned short*)((char*)d_ws + wsB_bytes);

  const int nwave      = NROWS / 64;                         // 3125
  const int mainBlocks = (nwave * 64 + 255) / 256;           // 782

  if (ws_size >= wsB_bytes + fb_bytes) {
    prep_weight_kernel<<<27, 256, 0, stream>>>(weight, wsB);
    prep_feats_kernel<<<((NROWS + 1) * CIN / 8 + 255) / 256, 256, 0, stream>>>(
        feats, (short8*)featsbf);
    spconv_mfma_kernel<0><<<mainBlocks, 256, 0, stream>>>(
        feats, featsbf, wsB, bias, in_idx, out);
  } else if (ws_size >= wsB_bytes) {
    prep_weight_kernel<<<27, 256, 0, stream>>>(weight, wsB);
    spconv_mfma_kernel<1><<<mainBlocks, 256, 0, stream>>>(
        feats, featsbf, wsB, bias, in_idx, out);
  } else {
    spconv_naive_kernel<<<(NROWS * COUT + 255) / 256, 256, 0, stream>>>(
        feats, weight, bias, in_idx, out);
  }
}